// Round 17
// baseline (319.493 us; speedup 1.0000x reference)
//
#include <hip/hip_runtime.h>
#include <hip/hip_bf16.h>
#include <math.h>

#define B_    8
#define N_TOK 1024
#define C_    768
#define H_    12
#define D_    64
#define HID_  3072

typedef __attribute__((ext_vector_type(4)))  float f32x4;
typedef __attribute__((ext_vector_type(16))) float f32x16;
typedef __attribute__((ext_vector_type(8)))  short s16x8;
typedef __attribute__((ext_vector_type(4)))  unsigned short u16x4;

static __device__ __forceinline__ unsigned short f2bf(float x){
  union { __hip_bfloat16 h; unsigned short u; } cv;
  cv.h = __float2bfloat16(x);
  return cv.u;
}
static __device__ __forceinline__ float bf2f(unsigned short u){
  return __uint_as_float(((unsigned)u) << 16);
}

#define GLOAD_LDS16(gp, lp) \
  __builtin_amdgcn_global_load_lds((const __attribute__((address_space(1))) unsigned int*)(gp), \
                                   (__attribute__((address_space(3))) unsigned int*)(lp), 16, 0, 0)

// ---------------- fused fp32 -> bf16 convert of all weights + rel_bias + LN1 ----------------
__global__ __launch_bounds__(256) void k_cvtall(
    const float* __restrict__ wq,  const float* __restrict__ wp,
    const float* __restrict__ w1t, const float* __restrict__ w2t,
    const float* __restrict__ w1i, const float* __restrict__ w2i,
    const float* __restrict__ bias,
    unsigned short* __restrict__ dq,  unsigned short* __restrict__ dp,
    unsigned short* __restrict__ d1t, unsigned short* __restrict__ d2t,
    unsigned short* __restrict__ d1i, unsigned short* __restrict__ d2i,
    unsigned short* __restrict__ db,
    const float* __restrict__ x,
    const float* __restrict__ ln1g, const float* __restrict__ ln1b,
    unsigned short* __restrict__ hln)
{
  if (blockIdx.x >= 23808){
    int row  = (blockIdx.x - 23808)*4 + (threadIdx.x >> 6);
    int lane = threadIdx.x & 63;
    const float* xr = x + (size_t)row*C_;
    float v[12]; float s = 0.f;
    #pragma unroll
    for (int i=0;i<12;i++){ v[i] = xr[lane + i*64]; s += v[i]; }
    #pragma unroll
    for (int m=1;m<64;m<<=1) s += __shfl_xor(s, m);
    float mu = s * (1.f/768.f);
    float vs = 0.f;
    #pragma unroll
    for (int i=0;i<12;i++){ float d = v[i]-mu; vs += d*d; }
    #pragma unroll
    for (int m=1;m<64;m<<=1) vs += __shfl_xor(vs, m);
    float rs = rsqrtf(vs*(1.f/768.f) + 1e-5f);
    unsigned short* orow = hln + (size_t)row*C_;
    #pragma unroll
    for (int i=0;i<12;i++){ int c = lane + i*64; orow[c] = f2bf((v[i]-mu)*rs*ln1g[c] + ln1b[c]); }
    return;
  }
  int i = blockIdx.x * 256 + threadIdx.x;
  const float* src; unsigned short* dst; int o;
  if      (i <  442368){ src = wq;  dst = dq;  o = i; }
  else if (i <  589824){ src = wp;  dst = dp;  o = i -  442368; }
  else if (i < 1179648){ src = w1t; dst = d1t; o = i -  589824; }
  else if (i < 1769472){ src = w2t; dst = d2t; o = i - 1179648; }
  else if (i < 2359296){ src = w1i; dst = d1i; o = i - 1769472; }
  else if (i < 2949120){ src = w2i; dst = d2i; o = i - 2359296; }
  else                 { src = bias;dst = db;  o = i - 2949120; }
  float4 v = ((const float4*)src)[o];
  u16x4 r;
  r.x = f2bf(v.x); r.y = f2bf(v.y); r.z = f2bf(v.z); r.w = f2bf(v.w);
  *(u16x4*)(dst + (size_t)o*4) = r;
}

// ---------------- LN2 (split text/image, compacted output) ----------------
__global__ __launch_bounds__(256) void k_ln2(const float* __restrict__ xmid,
                                             const float* __restrict__ gt, const float* __restrict__ bt,
                                             const float* __restrict__ gi, const float* __restrict__ bi,
                                             unsigned short* __restrict__ outc){
  int row  = blockIdx.x*4 + (threadIdx.x >> 6);
  int lane = threadIdx.x & 63;
  int bb = row >> 10, n = row & 1023;
  const float* G = (n < 512) ? gt : gi;
  const float* Bb = (n < 512) ? bt : bi;
  int crow = (n < 512) ? (bb*512 + n) : (4096 + bb*512 + (n - 512));
  const float* xr = xmid + (size_t)row*C_;
  float v[12]; float s = 0.f;
  #pragma unroll
  for (int i=0;i<12;i++){ v[i] = xr[lane + i*64]; s += v[i]; }
  #pragma unroll
  for (int m=1;m<64;m<<=1) s += __shfl_xor(s, m);
  float mu = s * (1.f/768.f);
  float vs = 0.f;
  #pragma unroll
  for (int i=0;i<12;i++){ float d = v[i]-mu; vs += d*d; }
  #pragma unroll
  for (int m=1;m<64;m<<=1) vs += __shfl_xor(vs, m);
  float rs = rsqrtf(vs*(1.f/768.f) + 1e-5f);
  unsigned short* orow = outc + (size_t)crow*C_;
  #pragma unroll
  for (int i=0;i<12;i++){ int c = lane + i*64; orow[c] = f2bf((v[i]-mu)*rs*G[c] + Bb[c]); }
}

// ---------------- pipelined bf16 GEMM, 32x32x16 MFMA (R10/R13 proven) ----------------
template<int MODE, int TM>
__global__ __launch_bounds__(TM==256 ? 512 : 256, TM==256 ? 2 : 3) void k_gemm2(
    const unsigned short* __restrict__ A,
    const unsigned short* __restrict__ Bw0,
    const unsigned short* __restrict__ Bw1,
    int K,
    const float* __restrict__ bias0,
    const float* __restrict__ bias1,
    const float* __restrict__ qb2,
    const float* __restrict__ resid,
    const float* __restrict__ gamma,
    unsigned short* __restrict__ out_bf,
    float* __restrict__ out_f)
{
  constexpr int THREADS = (TM == 256) ? 512 : 256;
  constexpr int ASLOT = TM * 64;
  constexpr int SLOT  = ASLOT + 8192;
  constexpr int BITS  = 8192 / (THREADS * 16);
  __shared__ __align__(16) char smem[3 * SLOT];
  const int tid = threadIdx.x;
  const int lane = tid & 63, w = tid >> 6;
  const int wr = w >> 1, wc = w & 1;
  const int l31 = lane & 31, h5 = lane >> 5;

  const int gx = gridDim.x, gy = gridDim.y;
  const int nwg = gx * gy;
  const int flat = blockIdx.y * gx + blockIdx.x;
  const int nid = (flat & 7) * (nwg >> 3) + (flat >> 3);
  const int by = nid % gy, bx = nid / gy;      // column-fast within XCD chunk
  const int z = blockIdx.z;
  const int row0 = bx*TM, col0 = by*128;

  const unsigned short* Ap = A;
  const unsigned short* Bp = Bw0;
  const float* bias = bias0;
  if (MODE == 2 || MODE == 3){
    if (z){ Ap = A + (size_t)4096*K; Bp = Bw1; bias = bias1; }
  }
  const char* Abase = (const char*)Ap;
  const char* Bbase = (const char*)Bp;
  const size_t rowbytes = (size_t)K*2;
  const int KT2 = K >> 5;

  auto stage = [&](int h, int slot_idx){
    char* slot = smem + slot_idx*SLOT;
    size_t kb = (size_t)h*64;
    #pragma unroll
    for (int it = 0; it < 2; it++){
      int L = it*(THREADS*16) + tid*16;
      int r = L >> 6, cb = L & 63;
      GLOAD_LDS16(Abase + (size_t)(row0 + r)*rowbytes + kb + (cb ^ ((r & 6) << 3)), slot + L);
    }
    #pragma unroll
    for (int it = 0; it < BITS; it++){
      int L = it*(THREADS*16) + tid*16;
      int r = L >> 6, cb = L & 63;
      GLOAD_LDS16(Bbase + (size_t)(col0 + r)*rowbytes + kb + (cb ^ ((r & 6) << 3)), slot + ASLOT + L);
    }
  };

  stage(0, 0); stage(1, 1);
  if constexpr (TM == 256) asm volatile("s_waitcnt vmcnt(3)" ::: "memory");
  else                     asm volatile("s_waitcnt vmcnt(4)" ::: "memory");
  __builtin_amdgcn_s_barrier();

  f32x16 acc[2][2] = {};
  int sh = 2, sc_ = 0;
  for (int h = 0; h < KT2; h++){
    if (h + 2 < KT2){
      stage(h + 2, sh);
      sh = (sh == 2) ? 0 : sh + 1;
    }
    char* slot = smem + sc_*SLOT;
    sc_ = (sc_ == 2) ? 0 : sc_ + 1;
    s16x8 af[2][2], bfr[2][2];
    #pragma unroll
    for (int fm = 0; fm < 2; fm++){
      int ra = wr*64 + fm*32 + l31;
      int swa = (ra & 6) << 3;
      af[fm][0] = *(const s16x8*)(slot + ra*64 + ((h5*16) ^ swa));
      af[fm][1] = *(const s16x8*)(slot + ra*64 + ((32 + h5*16) ^ swa));
    }
    #pragma unroll
    for (int fn = 0; fn < 2; fn++){
      int rb = wc*64 + fn*32 + l31;
      int swb = (rb & 6) << 3;
      bfr[fn][0] = *(const s16x8*)(slot + ASLOT + rb*64 + ((h5*16) ^ swb));
      bfr[fn][1] = *(const s16x8*)(slot + ASLOT + rb*64 + ((32 + h5*16) ^ swb));
    }
    __builtin_amdgcn_s_setprio(1);
    #pragma unroll
    for (int kh = 0; kh < 2; kh++)
      #pragma unroll
      for (int fm = 0; fm < 2; fm++)
        #pragma unroll
        for (int fn = 0; fn < 2; fn++)
          acc[fm][fn] = __builtin_amdgcn_mfma_f32_32x32x16_bf16(af[fm][kh], bfr[fn][kh], acc[fm][fn], 0, 0, 0);
    __builtin_amdgcn_s_setprio(0);
    if (h + 1 < KT2){
      if (h + 2 < KT2){
        if constexpr (TM == 256) asm volatile("s_waitcnt vmcnt(3)" ::: "memory");
        else                     asm volatile("s_waitcnt vmcnt(4)" ::: "memory");
      } else {
        asm volatile("s_waitcnt vmcnt(0)" ::: "memory");
      }
      __builtin_amdgcn_s_barrier();
    }
  }

  #pragma unroll
  for (int fm = 0; fm < 2; fm++){
    #pragma unroll
    for (int fn = 0; fn < 2; fn++){
      int j = col0 + wc*64 + fn*32 + l31;
      f32x16 a = acc[fm][fn];
      if (MODE == 0){
        int which = (j >= 1536) ? 2 : (j >= 768 ? 1 : 0);
        int cj = j - which*768;
        float bs = (which == 0) ? bias0[cj] : (which == 2 ? qb2[cj] : 0.f);
        int head = cj >> 6, d = cj & 63;
        #pragma unroll
        for (int r = 0; r < 16; r++){
          int m = row0 + wr*64 + fm*32 + (r & 3) + 8*(r >> 2) + 4*h5;
          int bb = m >> 10, n = m & 1023;
          float val = a[r] + bs;
          if (which == 0) val *= 0.125f;
          out_bf[((((size_t)which*B_ + bb)*H_ + head)*N_TOK + n)*D_ + d] = f2bf(val);
        }
      } else if (MODE == 1){
        float gm = gamma[j], bs = bias[j];
        #pragma unroll
        for (int r = 0; r < 16; r++){
          int m = row0 + wr*64 + fm*32 + (r & 3) + 8*(r >> 2) + 4*h5;
          size_t idx = (size_t)m*C_ + j;
          out_f[idx] = resid[idx] + gm*(a[r] + bs);
        }
      } else if (MODE == 2){
        float bs = bias[j];
        unsigned short* outp = out_bf + (size_t)z*4096*HID_;
        #pragma unroll
        for (int r = 0; r < 16; r++){
          int m = row0 + wr*64 + fm*32 + (r & 3) + 8*(r >> 2) + 4*h5;
          float t = a[r] + bs;
          outp[(size_t)m*HID_ + j] = f2bf(0.5f*t*(1.f + erff(t*0.70710678118654752f)));
        }
      } else {
        float gm = gamma[j], bs = bias[j];
        #pragma unroll
        for (int r = 0; r < 16; r++){
          int m = row0 + wr*64 + fm*32 + (r & 3) + 8*(r >> 2) + 4*h5;
          int bb = m >> 9, n = (m & 511) + (z ? 512 : 0);
          size_t idx = ((size_t)bb*N_TOK + n)*C_ + j;
          out_f[idx] = resid[idx] + gm*(a[r] + bs);
        }
      }
    }
  }
}

// ---------------- flash attention: 8 waves, 256-row q-tile (2x TLP per CU) ----------------
// Same proven per-wave body as R10/R16; K/V tiles shared across 2x the q-rows.
// 16 waves/CU (2 blocks x 8 waves), LDS 68KB.
__global__ __launch_bounds__(512, 2) void k_attn(
    const unsigned short* __restrict__ qb,
    const unsigned short* __restrict__ kb,
    const unsigned short* __restrict__ vb,
    const unsigned short* __restrict__ bias_bf,   // [H][N q][N k] bf16
    const int* __restrict__ mask,
    unsigned short* __restrict__ outb)
{
  __shared__ __align__(16) char smem[69632];
  char* Vt0 = smem;                       // 8 KB V^T dbuf
  char* Vt1 = smem + 8192;                // 8 KB
  char* Ks  = smem + 16384;               // 8 KB K tile [64 k][128 B], swizzled
  char* Bs  = smem + 24576;               // 32 KB bias tile [256 q][128 B], swizzled
  float* maskf = (float*)(smem + 57344);  // 4 KB
  char* Oep = smem;                       // epilogue overlay, 8 KB/wave x 8 = 64 KB

  int wg = blockIdx.x;
  int x = wg & 7, rest = wg >> 3;
  int qt = rest & 3, gl = rest >> 2;
  int g = gl*8 + x;
  int h = g % 12, bb = g / 12;

  const int tid = threadIdx.x, lane = tid & 63, w = tid >> 6;   // w in [0,8)
  const int l31 = lane & 31, h5 = lane >> 5;
  const size_t bh = (size_t)bb*H_ + h;
  const char* qp = (const char*)(qb + bh*N_TOK*D_);
  const char* kp = (const char*)(kb + bh*N_TOK*D_);
  const unsigned short* vp = vb + bh*N_TOK*D_;
  const char* bp = (const char*)(bias_bf + (size_t)h*N_TOK*N_TOK);
  const int q0 = qt*256;
  const int qrow = q0 + w*32 + l31;
  const int qr = w*32 + l31;              // block-local q row in [0,256)

  // ---- prologue: stage tile 0 ----
  {
    int L = tid*16; int r = L >> 7, cb = L & 127;
    GLOAD_LDS16(kp + (size_t)r*128 + (cb ^ ((r & 7) << 4)), Ks + L);
  }
  #pragma unroll
  for (int it = 0; it < 4; it++){
    int L = it*8192 + tid*16; int r = L >> 7, cb = L & 127;
    GLOAD_LDS16(bp + (size_t)(q0 + r)*2048 + (cb ^ ((r & 7) << 4)), Bs + L);
  }
  unsigned short vv[8];
  #pragma unroll
  for (int j = 0; j < 8; j++) vv[j] = vp[(size_t)(w*8 + j)*D_ + lane];
  if (tid < 256){
    int4 m4 = *(const int4*)(mask + bb*N_TOK + tid*4);
    float4 f4;
    f4.x = m4.x ? 0.f : -1e30f; f4.y = m4.y ? 0.f : -1e30f;
    f4.z = m4.z ? 0.f : -1e30f; f4.w = m4.w ? 0.f : -1e30f;
    *(float4*)(maskf + tid*4) = f4;
  }
  s16x8 qf[4];
  #pragma unroll
  for (int t = 0; t < 4; t++)
    qf[t] = *(const s16x8*)(qp + (size_t)qrow*128 + t*32 + h5*16);
  {
    s16x8 pk;
    #pragma unroll
    for (int e = 0; e < 8; e++) pk[e] = (short)vv[e];
    *(s16x8*)(Vt0 + lane*128 + ((w*16) ^ ((lane & 7) << 4))) = pk;
  }
  __syncthreads();

  f32x16 oacc[2] = {};
  float lrow = 0.f;

  for (int t = 0; t < 16; t++){
    const int kt = t*64;
    char* Vbuf = (t & 1) ? Vt1 : Vt0;
    char* Vnxt = (t & 1) ? Vt0 : Vt1;

    s16x8 kfr[2][4];
    #pragma unroll
    for (int ck = 0; ck < 2; ck++)
      #pragma unroll
      for (int tt = 0; tt < 4; tt++)
        kfr[ck][tt] = *(const s16x8*)(Ks + (ck*32 + l31)*128 + ((tt*32 + h5*16) ^ ((l31 & 7) << 4)));
    u16x4 bv[2][4];
    #pragma unroll
    for (int ck = 0; ck < 2; ck++)
      #pragma unroll
      for (int rq = 0; rq < 4; rq++){
        int off = ck*64 + rq*16 + h5*8;
        bv[ck][rq] = *(const u16x4*)(Bs + qr*128 + (off ^ ((qr & 7) << 4)));
      }
    __syncthreads();

    if (t < 15){
      {
        int L = tid*16; int r = L >> 7, cb = L & 127;
        GLOAD_LDS16(kp + (size_t)(kt + 64 + r)*128 + (cb ^ ((r & 7) << 4)), Ks + L);
      }
      #pragma unroll
      for (int it = 0; it < 4; it++){
        int L = it*8192 + tid*16; int r = L >> 7, cb = L & 127;
        GLOAD_LDS16(bp + (size_t)(q0 + r)*2048 + (size_t)(kt + 64)*2 + (cb ^ ((r & 7) << 4)), Bs + L);
      }
      #pragma unroll
      for (int j = 0; j < 8; j++)
        vv[j] = vp[(size_t)(kt + 64 + w*8 + j)*D_ + lane];
    }

    f32x16 sacc[2] = {};
    __builtin_amdgcn_s_setprio(1);
    #pragma unroll
    for (int tt = 0; tt < 4; tt++){
      sacc[0] = __builtin_amdgcn_mfma_f32_32x32x16_bf16(kfr[0][tt], qf[tt], sacc[0], 0, 0, 0);
      sacc[1] = __builtin_amdgcn_mfma_f32_32x32x16_bf16(kfr[1][tt], qf[tt], sacc[1], 0, 0, 0);
    }
    __builtin_amdgcn_s_setprio(0);

    // p = __expf(S + bias + maskadd), fixed max 0
    float sv[2][16];
    float ps = 0.f;
    #pragma unroll
    for (int ck = 0; ck < 2; ck++){
      #pragma unroll
      for (int r = 0; r < 16; r++){
        int kk = ck*32 + (r & 3) + 8*(r >> 2) + 4*h5;
        float p = __expf(sacc[ck][r] + bf2f(bv[ck][r >> 2][r & 3]) + maskf[kt + kk]);
        sv[ck][r] = p;
        ps += p;
      }
    }
    lrow += ps;

    #pragma unroll
    for (int ck = 0; ck < 2; ck++){
      #pragma unroll
      for (int kh = 0; kh < 2; kh++){
        unsigned wA, wB, wC, wD;
        asm("v_cvt_pk_bf16_f32 %0, %1, %2" : "=v"(wA) : "v"(sv[ck][kh*8+0]), "v"(sv[ck][kh*8+1]));
        asm("v_cvt_pk_bf16_f32 %0, %1, %2" : "=v"(wB) : "v"(sv[ck][kh*8+2]), "v"(sv[ck][kh*8+3]));
        asm("v_cvt_pk_bf16_f32 %0, %1, %2" : "=v"(wC) : "v"(sv[ck][kh*8+4]), "v"(sv[ck][kh*8+5]));
        asm("v_cvt_pk_bf16_f32 %0, %1, %2" : "=v"(wD) : "v"(sv[ck][kh*8+6]), "v"(sv[ck][kh*8+7]));
        unsigned tA = (unsigned)__shfl_xor((int)wA, 32);
        unsigned tB = (unsigned)__shfl_xor((int)wB, 32);
        unsigned tC = (unsigned)__shfl_xor((int)wC, 32);
        unsigned tD = (unsigned)__shfl_xor((int)wD, 32);
        union { unsigned u[4]; s16x8 v; } pu;
        pu.u[0] = h5 ? tC : wA;
        pu.u[1] = h5 ? tD : wB;
        pu.u[2] = h5 ? wC : tA;
        pu.u[3] = h5 ? wD : tB;
        __builtin_amdgcn_s_setprio(1);
        #pragma unroll
        for (int dt = 0; dt < 2; dt++){
          int d = dt*32 + l31;
          s16x8 vf = *(const s16x8*)(Vbuf + d*128 + ((ck*64 + kh*32 + h5*16) ^ ((d & 7) << 4)));
          oacc[dt] = __builtin_amdgcn_mfma_f32_32x32x16_bf16(vf, pu.v, oacc[dt], 0, 0, 0);
        }
        __builtin_amdgcn_s_setprio(0);
      }
    }

    if (t < 15){
      s16x8 pk;
      #pragma unroll
      for (int e = 0; e < 8; e++) pk[e] = (short)vv[e];
      *(s16x8*)(Vnxt + lane*128 + ((w*16) ^ ((lane & 7) << 4))) = pk;
    }
    __syncthreads();
  }

  // ---- epilogue: normalize, transpose via wave-private LDS overlay, coalesced store ----
  lrow += __shfl_xor(lrow, 32);
  float inv = 1.f / lrow;
  char* Ow = Oep + w*8192;
  #pragma unroll
  for (int dt = 0; dt < 2; dt++)
    #pragma unroll
    for (int r = 0; r < 16; r++){
      int d = dt*32 + (r & 3) + 8*(r >> 2) + 4*h5;
      *(float*)(Ow + l31*256 + ((d*4) ^ ((l31 & 7) << 4))) = oacc[dt][r] * inv;
    }
  int q2 = lane >> 1, dh = lane & 1;
  float of[32];
  #pragma unroll
  for (int i = 0; i < 8; i++){
    f32x4 v4 = *(const f32x4*)(Ow + q2*256 + ((dh*128 + i*16) ^ ((q2 & 7) << 4)));
    of[i*4+0] = v4[0]; of[i*4+1] = v4[1]; of[i*4+2] = v4[2]; of[i*4+3] = v4[3];
  }
  unsigned short* orow = outb + ((size_t)bb*N_TOK + q0 + w*32 + q2)*C_ + h*64 + dh*32;
  #pragma unroll
  for (int i = 0; i < 4; i++){
    s16x8 ob;
    #pragma unroll
    for (int e = 0; e < 8; e++) ob[e] = (short)f2bf(of[i*8+e]);
    *(s16x8*)(orow + i*8) = ob;
  }
}

extern "C" void kernel_launch(void* const* d_in, const int* in_sizes, int n_in,
                              void* d_out, int out_size, void* d_ws, size_t ws_size,
                              hipStream_t stream) {
  const float* x      = (const float*)d_in[0];
  const int*   mask   = (const int*)  d_in[1];
  const float* relb   = (const float*)d_in[2];
  const float* w_qkv  = (const float*)d_in[3];
  const float* q_bias = (const float*)d_in[4];
  const float* v_bias = (const float*)d_in[5];
  const float* w_proj = (const float*)d_in[6];
  const float* b_proj = (const float*)d_in[7];
  const float* ln1_g  = (const float*)d_in[8];
  const float* ln1_b  = (const float*)d_in[9];
  const float* ln2t_g = (const float*)d_in[10];
  const float* ln2t_b = (const float*)d_in[11];
  const float* ln2i_g = (const float*)d_in[12];
  const float* ln2i_b = (const float*)d_in[13];
  const float* w1t    = (const float*)d_in[14];
  const float* b1t    = (const float*)d_in[15];
  const float* w2t    = (const float*)d_in[16];
  const float* b2t    = (const float*)d_in[17];
  const float* w1i    = (const float*)d_in[18];
  const float* b1i    = (const float*)d_in[19];
  const float* w2i    = (const float*)d_in[20];
  const float* b2i    = (const float*)d_in[21];
  const float* gamma1 = (const float*)d_in[22];
  const float* gamma2 = (const float*)d_in[23];
  float* out = (float*)d_out;
  char* ws = (char*)d_ws;

  size_t off = 0;
  auto nxt = [&](size_t b){ size_t r = off; off += (b + 255) & ~(size_t)255; return r; };
  unsigned short* wq_bf  = (unsigned short*)(ws + nxt((size_t)3*C_*C_*2));
  unsigned short* wp_bf  = (unsigned short*)(ws + nxt((size_t)C_*C_*2));
  unsigned short* w1t_bf = (unsigned short*)(ws + nxt((size_t)HID_*C_*2));
  unsigned short* w2t_bf = (unsigned short*)(ws + nxt((size_t)HID_*C_*2));
  unsigned short* w1i_bf = (unsigned short*)(ws + nxt((size_t)HID_*C_*2));
  unsigned short* w2i_bf = (unsigned short*)(ws + nxt((size_t)HID_*C_*2));
  unsigned short* hln    = (unsigned short*)(ws + nxt((size_t)B_*N_TOK*C_*2));   // reused as ln2c
  unsigned short* qkv    = (unsigned short*)(ws + nxt((size_t)3*B_*N_TOK*C_*2)); // reused as hidden
  unsigned short* attno  = (unsigned short*)(ws + nxt((size_t)B_*N_TOK*C_*2));
  float*          xmid   = (float*)(ws + nxt((size_t)B_*N_TOK*C_*4));
  unsigned short* ln2c   = hln;
  unsigned short* hidden = qkv;
  // bias_bf [H][N][N] bf16 overlays xmid exactly (both 25165824 B); attention reads it
  // BEFORE proj writes xmid — stream-ordered, deterministic across graph replays.
  unsigned short* bias_bf = (unsigned short*)xmid;

  // conversions + LN1 fused: 23808 convert blocks + 2048 LN1 blocks
  k_cvtall<<<dim3(25856), 256, 0, stream>>>(w_qkv, w_proj, w1t, w2t, w1i, w2i, relb,
                                            wq_bf, wp_bf, w1t_bf, w2t_bf, w1i_bf, w2i_bf, bias_bf,
                                            x, ln1_g, ln1_b, hln);

  // QKV GEMM: [8192][768] @ [2304][768]^T  (256-row tile, q*0.125 in epilogue)
  k_gemm2<0,256><<<dim3(32, 18, 1), 512, 0, stream>>>(hln, wq_bf, nullptr, C_,
                                                      q_bias, nullptr, v_bias,
                                                      nullptr, nullptr, qkv, nullptr);

  // attention (1D grid of 384, 8 waves / 256 q-rows per block, XCD-aware decode)
  const size_t qsz = (size_t)B_*H_*N_TOK*D_;
  k_attn<<<dim3(384), 512, 0, stream>>>(qkv, qkv + qsz, qkv + 2*qsz, bias_bf, mask, attno);

  // proj + residual -> xmid (fp32)
  k_gemm2<1,128><<<dim3(64, 6, 1), 256, 0, stream>>>(attno, wp_bf, nullptr, C_,
                                                     b_proj, nullptr, nullptr,
                                                     x, gamma1, nullptr, xmid);

  // LN2 (compacted text/image)
  k_ln2<<<dim3(B_*N_TOK/4), 256, 0, stream>>>(xmid, ln2t_g, ln2t_b, ln2i_g, ln2i_b, ln2c);

  // MLP fc1 + exact GELU (256-row tile; text z=0, image z=1)
  k_gemm2<2,256><<<dim3(16, 24, 2), 512, 0, stream>>>(ln2c, w1t_bf, w1i_bf, C_,
                                                      b1t, b1i, nullptr,
                                                      nullptr, nullptr, hidden, nullptr);

  // MLP fc2 + residual -> d_out (text z=0, image z=1)
  k_gemm2<3,128><<<dim3(32, 6, 2), 256, 0, stream>>>(hidden, w2t_bf, w2i_bf, HID_,
                                                     b2t, b2i, nullptr,
                                                     xmid, gamma2, nullptr, out);
}

// Round 18
// 304.128 us; speedup vs baseline: 1.0505x; 1.0505x over previous
//
#include <hip/hip_runtime.h>
#include <hip/hip_bf16.h>
#include <math.h>

#define B_    8
#define N_TOK 1024
#define C_    768
#define H_    12
#define D_    64
#define HID_  3072

typedef __attribute__((ext_vector_type(4)))  float f32x4;
typedef __attribute__((ext_vector_type(16))) float f32x16;
typedef __attribute__((ext_vector_type(8)))  short s16x8;
typedef __attribute__((ext_vector_type(4)))  unsigned short u16x4;

static __device__ __forceinline__ unsigned short f2bf(float x){
  union { __hip_bfloat16 h; unsigned short u; } cv;
  cv.h = __float2bfloat16(x);
  return cv.u;
}
static __device__ __forceinline__ float bf2f(unsigned short u){
  return __uint_as_float(((unsigned)u) << 16);
}

#define GLOAD_LDS16(gp, lp) \
  __builtin_amdgcn_global_load_lds((const __attribute__((address_space(1))) unsigned int*)(gp), \
                                   (__attribute__((address_space(3))) unsigned int*)(lp), 16, 0, 0)

// ---------------- fused fp32 -> bf16 convert of all weights + rel_bias + LN1 ----------------
__global__ __launch_bounds__(256) void k_cvtall(
    const float* __restrict__ wq,  const float* __restrict__ wp,
    const float* __restrict__ w1t, const float* __restrict__ w2t,
    const float* __restrict__ w1i, const float* __restrict__ w2i,
    const float* __restrict__ bias,
    unsigned short* __restrict__ dq,  unsigned short* __restrict__ dp,
    unsigned short* __restrict__ d1t, unsigned short* __restrict__ d2t,
    unsigned short* __restrict__ d1i, unsigned short* __restrict__ d2i,
    unsigned short* __restrict__ db,
    const float* __restrict__ x,
    const float* __restrict__ ln1g, const float* __restrict__ ln1b,
    unsigned short* __restrict__ hln)
{
  if (blockIdx.x >= 23808){
    int row  = (blockIdx.x - 23808)*4 + (threadIdx.x >> 6);
    int lane = threadIdx.x & 63;
    const float* xr = x + (size_t)row*C_;
    float v[12]; float s = 0.f;
    #pragma unroll
    for (int i=0;i<12;i++){ v[i] = xr[lane + i*64]; s += v[i]; }
    #pragma unroll
    for (int m=1;m<64;m<<=1) s += __shfl_xor(s, m);
    float mu = s * (1.f/768.f);
    float vs = 0.f;
    #pragma unroll
    for (int i=0;i<12;i++){ float d = v[i]-mu; vs += d*d; }
    #pragma unroll
    for (int m=1;m<64;m<<=1) vs += __shfl_xor(vs, m);
    float rs = rsqrtf(vs*(1.f/768.f) + 1e-5f);
    unsigned short* orow = hln + (size_t)row*C_;
    #pragma unroll
    for (int i=0;i<12;i++){ int c = lane + i*64; orow[c] = f2bf((v[i]-mu)*rs*ln1g[c] + ln1b[c]); }
    return;
  }
  int i = blockIdx.x * 256 + threadIdx.x;
  const float* src; unsigned short* dst; int o;
  if      (i <  442368){ src = wq;  dst = dq;  o = i; }
  else if (i <  589824){ src = wp;  dst = dp;  o = i -  442368; }
  else if (i < 1179648){ src = w1t; dst = d1t; o = i -  589824; }
  else if (i < 1769472){ src = w2t; dst = d2t; o = i - 1179648; }
  else if (i < 2359296){ src = w1i; dst = d1i; o = i - 1769472; }
  else if (i < 2949120){ src = w2i; dst = d2i; o = i - 2359296; }
  else                 { src = bias;dst = db;  o = i - 2949120; }
  float4 v = ((const float4*)src)[o];
  u16x4 r;
  r.x = f2bf(v.x); r.y = f2bf(v.y); r.z = f2bf(v.z); r.w = f2bf(v.w);
  *(u16x4*)(dst + (size_t)o*4) = r;
}

// ---------------- LN2 (split text/image, compacted output) ----------------
__global__ __launch_bounds__(256) void k_ln2(const float* __restrict__ xmid,
                                             const float* __restrict__ gt, const float* __restrict__ bt,
                                             const float* __restrict__ gi, const float* __restrict__ bi,
                                             unsigned short* __restrict__ outc){
  int row  = blockIdx.x*4 + (threadIdx.x >> 6);
  int lane = threadIdx.x & 63;
  int bb = row >> 10, n = row & 1023;
  const float* G = (n < 512) ? gt : gi;
  const float* Bb = (n < 512) ? bt : bi;
  int crow = (n < 512) ? (bb*512 + n) : (4096 + bb*512 + (n - 512));
  const float* xr = xmid + (size_t)row*C_;
  float v[12]; float s = 0.f;
  #pragma unroll
  for (int i=0;i<12;i++){ v[i] = xr[lane + i*64]; s += v[i]; }
  #pragma unroll
  for (int m=1;m<64;m<<=1) s += __shfl_xor(s, m);
  float mu = s * (1.f/768.f);
  float vs = 0.f;
  #pragma unroll
  for (int i=0;i<12;i++){ float d = v[i]-mu; vs += d*d; }
  #pragma unroll
  for (int m=1;m<64;m<<=1) vs += __shfl_xor(vs, m);
  float rs = rsqrtf(vs*(1.f/768.f) + 1e-5f);
  unsigned short* orow = outc + (size_t)crow*C_;
  #pragma unroll
  for (int i=0;i<12;i++){ int c = lane + i*64; orow[c] = f2bf((v[i]-mu)*rs*G[c] + Bb[c]); }
}

// ---------------- pipelined bf16 GEMM, 32x32x16 MFMA (R10/R13 proven) ----------------
// TM x 128 tile, 32-elem K-halves into 3 rotating slots, depth-2 prefetch, counted vmcnt,
// raw s_barrier, setprio, XCD-bijective swizzle, column-fast decode per XCD chunk.
template<int MODE, int TM>
__global__ __launch_bounds__(TM==256 ? 512 : 256, TM==256 ? 2 : 3) void k_gemm2(
    const unsigned short* __restrict__ A,
    const unsigned short* __restrict__ Bw0,
    const unsigned short* __restrict__ Bw1,
    int K,
    const float* __restrict__ bias0,
    const float* __restrict__ bias1,
    const float* __restrict__ qb2,
    const float* __restrict__ resid,
    const float* __restrict__ gamma,
    unsigned short* __restrict__ out_bf,
    float* __restrict__ out_f)
{
  constexpr int THREADS = (TM == 256) ? 512 : 256;
  constexpr int ASLOT = TM * 64;
  constexpr int SLOT  = ASLOT + 8192;
  constexpr int BITS  = 8192 / (THREADS * 16);
  __shared__ __align__(16) char smem[3 * SLOT];
  const int tid = threadIdx.x;
  const int lane = tid & 63, w = tid >> 6;
  const int wr = w >> 1, wc = w & 1;
  const int l31 = lane & 31, h5 = lane >> 5;

  const int gx = gridDim.x, gy = gridDim.y;
  const int nwg = gx * gy;
  const int flat = blockIdx.y * gx + blockIdx.x;
  const int nid = (flat & 7) * (nwg >> 3) + (flat >> 3);
  const int by = nid % gy, bx = nid / gy;      // column-fast within XCD chunk
  const int z = blockIdx.z;
  const int row0 = bx*TM, col0 = by*128;

  const unsigned short* Ap = A;
  const unsigned short* Bp = Bw0;
  const float* bias = bias0;
  if (MODE == 2 || MODE == 3){
    if (z){ Ap = A + (size_t)4096*K; Bp = Bw1; bias = bias1; }
  }
  const char* Abase = (const char*)Ap;
  const char* Bbase = (const char*)Bp;
  const size_t rowbytes = (size_t)K*2;
  const int KT2 = K >> 5;

  auto stage = [&](int h, int slot_idx){
    char* slot = smem + slot_idx*SLOT;
    size_t kb = (size_t)h*64;
    #pragma unroll
    for (int it = 0; it < 2; it++){
      int L = it*(THREADS*16) + tid*16;
      int r = L >> 6, cb = L & 63;
      GLOAD_LDS16(Abase + (size_t)(row0 + r)*rowbytes + kb + (cb ^ ((r & 6) << 3)), slot + L);
    }
    #pragma unroll
    for (int it = 0; it < BITS; it++){
      int L = it*(THREADS*16) + tid*16;
      int r = L >> 6, cb = L & 63;
      GLOAD_LDS16(Bbase + (size_t)(col0 + r)*rowbytes + kb + (cb ^ ((r & 6) << 3)), slot + ASLOT + L);
    }
  };

  stage(0, 0); stage(1, 1);
  if constexpr (TM == 256) asm volatile("s_waitcnt vmcnt(3)" ::: "memory");
  else                     asm volatile("s_waitcnt vmcnt(4)" ::: "memory");
  __builtin_amdgcn_s_barrier();

  f32x16 acc[2][2] = {};
  int sh = 2, sc_ = 0;
  for (int h = 0; h < KT2; h++){
    if (h + 2 < KT2){
      stage(h + 2, sh);
      sh = (sh == 2) ? 0 : sh + 1;
    }
    char* slot = smem + sc_*SLOT;
    sc_ = (sc_ == 2) ? 0 : sc_ + 1;
    s16x8 af[2][2], bfr[2][2];
    #pragma unroll
    for (int fm = 0; fm < 2; fm++){
      int ra = wr*64 + fm*32 + l31;
      int swa = (ra & 6) << 3;
      af[fm][0] = *(const s16x8*)(slot + ra*64 + ((h5*16) ^ swa));
      af[fm][1] = *(const s16x8*)(slot + ra*64 + ((32 + h5*16) ^ swa));
    }
    #pragma unroll
    for (int fn = 0; fn < 2; fn++){
      int rb = wc*64 + fn*32 + l31;
      int swb = (rb & 6) << 3;
      bfr[fn][0] = *(const s16x8*)(slot + ASLOT + rb*64 + ((h5*16) ^ swb));
      bfr[fn][1] = *(const s16x8*)(slot + ASLOT + rb*64 + ((32 + h5*16) ^ swb));
    }
    __builtin_amdgcn_s_setprio(1);
    #pragma unroll
    for (int kh = 0; kh < 2; kh++)
      #pragma unroll
      for (int fm = 0; fm < 2; fm++)
        #pragma unroll
        for (int fn = 0; fn < 2; fn++)
          acc[fm][fn] = __builtin_amdgcn_mfma_f32_32x32x16_bf16(af[fm][kh], bfr[fn][kh], acc[fm][fn], 0, 0, 0);
    __builtin_amdgcn_s_setprio(0);
    if (h + 1 < KT2){
      if (h + 2 < KT2){
        if constexpr (TM == 256) asm volatile("s_waitcnt vmcnt(3)" ::: "memory");
        else                     asm volatile("s_waitcnt vmcnt(4)" ::: "memory");
      } else {
        asm volatile("s_waitcnt vmcnt(0)" ::: "memory");
      }
      __builtin_amdgcn_s_barrier();
    }
  }

  #pragma unroll
  for (int fm = 0; fm < 2; fm++){
    #pragma unroll
    for (int fn = 0; fn < 2; fn++){
      int j = col0 + wc*64 + fn*32 + l31;
      f32x16 a = acc[fm][fn];
      if (MODE == 0){
        int which = (j >= 1536) ? 2 : (j >= 768 ? 1 : 0);
        int cj = j - which*768;
        float bs = (which == 0) ? bias0[cj] : (which == 2 ? qb2[cj] : 0.f);
        int head = cj >> 6, d = cj & 63;
        #pragma unroll
        for (int r = 0; r < 16; r++){
          int m = row0 + wr*64 + fm*32 + (r & 3) + 8*(r >> 2) + 4*h5;
          int bb = m >> 10, n = m & 1023;
          float val = a[r] + bs;
          if (which == 0) val *= 0.125f;
          out_bf[((((size_t)which*B_ + bb)*H_ + head)*N_TOK + n)*D_ + d] = f2bf(val);
        }
      } else if (MODE == 1){
        float gm = gamma[j], bs = bias[j];
        #pragma unroll
        for (int r = 0; r < 16; r++){
          int m = row0 + wr*64 + fm*32 + (r & 3) + 8*(r >> 2) + 4*h5;
          size_t idx = (size_t)m*C_ + j;
          out_f[idx] = resid[idx] + gm*(a[r] + bs);
        }
      } else if (MODE == 2){
        float bs = bias[j];
        unsigned short* outp = out_bf + (size_t)z*4096*HID_;
        #pragma unroll
        for (int r = 0; r < 16; r++){
          int m = row0 + wr*64 + fm*32 + (r & 3) + 8*(r >> 2) + 4*h5;
          float t = a[r] + bs;
          outp[(size_t)m*HID_ + j] = f2bf(0.5f*t*(1.f + erff(t*0.70710678118654752f)));
        }
      } else {
        float gm = gamma[j], bs = bias[j];
        #pragma unroll
        for (int r = 0; r < 16; r++){
          int m = row0 + wr*64 + fm*32 + (r & 3) + 8*(r >> 2) + 4*h5;
          int bb = m >> 9, n = (m & 511) + (z ? 512 : 0);
          size_t idx = ((size_t)bb*N_TOK + n)*C_ + j;
          out_f[idx] = resid[idx] + gm*(a[r] + bs);
        }
      }
    }
  }
}

// ---------------- flash attention, swapped-operand 32x32 MFMA (R10 proven body) ----------------
__global__ __launch_bounds__(256, 2) void k_attn(
    const unsigned short* __restrict__ qb,
    const unsigned short* __restrict__ kb,
    const unsigned short* __restrict__ vb,
    const unsigned short* __restrict__ bias_bf,   // [H][N q][N k] bf16
    const int* __restrict__ mask,
    unsigned short* __restrict__ outb)
{
  __shared__ __align__(16) char smem[45056];
  char* Vt0 = smem;
  char* Vt1 = smem + 8192;
  char* Ks  = smem + 16384;
  char* Bs  = smem + 24576;
  float* maskf = (float*)(smem + 40960);
  char* Oep = smem;

  int wg = blockIdx.x;
  int x = wg & 7, rest = wg >> 3;
  int qt = rest & 7, gl = rest >> 3;
  int g = gl*8 + x;
  int h = g % 12, bb = g / 12;

  const int tid = threadIdx.x, lane = tid & 63, w = tid >> 6;
  const int l31 = lane & 31, h5 = lane >> 5;
  const size_t bh = (size_t)bb*H_ + h;
  const char* qp = (const char*)(qb + bh*N_TOK*D_);
  const char* kp = (const char*)(kb + bh*N_TOK*D_);
  const unsigned short* vp = vb + bh*N_TOK*D_;
  const char* bp = (const char*)(bias_bf + (size_t)h*N_TOK*N_TOK);
  const int q0 = qt*128;
  const int qrow = q0 + w*32 + l31;
  const int qr = w*32 + l31;

  #pragma unroll
  for (int it = 0; it < 2; it++){
    int L = it*4096 + tid*16; int r = L >> 7, cb = L & 127;
    GLOAD_LDS16(kp + (size_t)r*128 + (cb ^ ((r & 7) << 4)), Ks + L);
  }
  #pragma unroll
  for (int it = 0; it < 4; it++){
    int L = it*4096 + tid*16; int r = L >> 7, cb = L & 127;
    GLOAD_LDS16(bp + (size_t)(q0 + r)*2048 + (cb ^ ((r & 7) << 4)), Bs + L);
  }
  unsigned short vv[16];
  #pragma unroll
  for (int j = 0; j < 16; j++) vv[j] = vp[(size_t)(w*16 + j)*D_ + lane];
  {
    int4 m4 = *(const int4*)(mask + bb*N_TOK + tid*4);
    float4 f4;
    f4.x = m4.x ? 0.f : -1e30f; f4.y = m4.y ? 0.f : -1e30f;
    f4.z = m4.z ? 0.f : -1e30f; f4.w = m4.w ? 0.f : -1e30f;
    *(float4*)(maskf + tid*4) = f4;
  }
  s16x8 qf[4];
  #pragma unroll
  for (int t = 0; t < 4; t++)
    qf[t] = *(const s16x8*)(qp + (size_t)qrow*128 + t*32 + h5*16);
  #pragma unroll
  for (int i = 0; i < 2; i++){
    s16x8 pk;
    #pragma unroll
    for (int e = 0; e < 8; e++) pk[e] = (short)vv[i*8 + e];
    *(s16x8*)(Vt0 + lane*128 + ((w*32 + i*16) ^ ((lane & 7) << 4))) = pk;
  }
  __syncthreads();

  f32x16 oacc[2] = {};
  float lrow = 0.f;

  for (int t = 0; t < 16; t++){
    const int kt = t*64;
    char* Vbuf = (t & 1) ? Vt1 : Vt0;
    char* Vnxt = (t & 1) ? Vt0 : Vt1;

    s16x8 kfr[2][4];
    #pragma unroll
    for (int ck = 0; ck < 2; ck++)
      #pragma unroll
      for (int tt = 0; tt < 4; tt++)
        kfr[ck][tt] = *(const s16x8*)(Ks + (ck*32 + l31)*128 + ((tt*32 + h5*16) ^ ((l31 & 7) << 4)));
    u16x4 bv[2][4];
    #pragma unroll
    for (int ck = 0; ck < 2; ck++)
      #pragma unroll
      for (int rq = 0; rq < 4; rq++){
        int off = ck*64 + rq*16 + h5*8;
        bv[ck][rq] = *(const u16x4*)(Bs + qr*128 + (off ^ ((qr & 7) << 4)));
      }
    __syncthreads();

    if (t < 15){
      #pragma unroll
      for (int it = 0; it < 2; it++){
        int L = it*4096 + tid*16; int r = L >> 7, cb = L & 127;
        GLOAD_LDS16(kp + (size_t)(kt + 64 + r)*128 + (cb ^ ((r & 7) << 4)), Ks + L);
      }
      #pragma unroll
      for (int it = 0; it < 4; it++){
        int L = it*4096 + tid*16; int r = L >> 7, cb = L & 127;
        GLOAD_LDS16(bp + (size_t)(q0 + r)*2048 + (size_t)(kt + 64)*2 + (cb ^ ((r & 7) << 4)), Bs + L);
      }
      #pragma unroll
      for (int j = 0; j < 16; j++)
        vv[j] = vp[(size_t)(kt + 64 + w*16 + j)*D_ + lane];
    }

    f32x16 sacc[2] = {};
    __builtin_amdgcn_s_setprio(1);
    #pragma unroll
    for (int tt = 0; tt < 4; tt++){
      sacc[0] = __builtin_amdgcn_mfma_f32_32x32x16_bf16(kfr[0][tt], qf[tt], sacc[0], 0, 0, 0);
      sacc[1] = __builtin_amdgcn_mfma_f32_32x32x16_bf16(kfr[1][tt], qf[tt], sacc[1], 0, 0, 0);
    }
    __builtin_amdgcn_s_setprio(0);

    // p = __expf(S + bias + maskadd), fixed max 0
    float sv[2][16];
    float ps = 0.f;
    #pragma unroll
    for (int ck = 0; ck < 2; ck++){
      #pragma unroll
      for (int r = 0; r < 16; r++){
        int kk = ck*32 + (r & 3) + 8*(r >> 2) + 4*h5;
        float p = __expf(sacc[ck][r] + bf2f(bv[ck][r >> 2][r & 3]) + maskf[kt + kk]);
        sv[ck][r] = p;
        ps += p;
      }
    }
    lrow += ps;

    #pragma unroll
    for (int ck = 0; ck < 2; ck++){
      #pragma unroll
      for (int kh = 0; kh < 2; kh++){
        unsigned wA, wB, wC, wD;
        asm("v_cvt_pk_bf16_f32 %0, %1, %2" : "=v"(wA) : "v"(sv[ck][kh*8+0]), "v"(sv[ck][kh*8+1]));
        asm("v_cvt_pk_bf16_f32 %0, %1, %2" : "=v"(wB) : "v"(sv[ck][kh*8+2]), "v"(sv[ck][kh*8+3]));
        asm("v_cvt_pk_bf16_f32 %0, %1, %2" : "=v"(wC) : "v"(sv[ck][kh*8+4]), "v"(sv[ck][kh*8+5]));
        asm("v_cvt_pk_bf16_f32 %0, %1, %2" : "=v"(wD) : "v"(sv[ck][kh*8+6]), "v"(sv[ck][kh*8+7]));
        unsigned tA = (unsigned)__shfl_xor((int)wA, 32);
        unsigned tB = (unsigned)__shfl_xor((int)wB, 32);
        unsigned tC = (unsigned)__shfl_xor((int)wC, 32);
        unsigned tD = (unsigned)__shfl_xor((int)wD, 32);
        union { unsigned u[4]; s16x8 v; } pu;
        pu.u[0] = h5 ? tC : wA;
        pu.u[1] = h5 ? tD : wB;
        pu.u[2] = h5 ? wC : tA;
        pu.u[3] = h5 ? wD : tB;
        __builtin_amdgcn_s_setprio(1);
        #pragma unroll
        for (int dt = 0; dt < 2; dt++){
          int d = dt*32 + l31;
          s16x8 vf = *(const s16x8*)(Vbuf + d*128 + ((ck*64 + kh*32 + h5*16) ^ ((d & 7) << 4)));
          oacc[dt] = __builtin_amdgcn_mfma_f32_32x32x16_bf16(vf, pu.v, oacc[dt], 0, 0, 0);
        }
        __builtin_amdgcn_s_setprio(0);
      }
    }

    if (t < 15){
      #pragma unroll
      for (int i = 0; i < 2; i++){
        s16x8 pk;
        #pragma unroll
        for (int e = 0; e < 8; e++) pk[e] = (short)vv[i*8 + e];
        *(s16x8*)(Vnxt + lane*128 + ((w*32 + i*16) ^ ((lane & 7) << 4))) = pk;
      }
    }
    __syncthreads();
  }

  lrow += __shfl_xor(lrow, 32);
  float inv = 1.f / lrow;
  char* Ow = Oep + w*8192;
  #pragma unroll
  for (int dt = 0; dt < 2; dt++)
    #pragma unroll
    for (int r = 0; r < 16; r++){
      int d = dt*32 + (r & 3) + 8*(r >> 2) + 4*h5;
      *(float*)(Ow + l31*256 + ((d*4) ^ ((l31 & 7) << 4))) = oacc[dt][r] * inv;
    }
  int q2 = lane >> 1, dh = lane & 1;
  float of[32];
  #pragma unroll
  for (int i = 0; i < 8; i++){
    f32x4 v4 = *(const f32x4*)(Ow + q2*256 + ((dh*128 + i*16) ^ ((q2 & 7) << 4)));
    of[i*4+0] = v4[0]; of[i*4+1] = v4[1]; of[i*4+2] = v4[2]; of[i*4+3] = v4[3];
  }
  unsigned short* orow = outb + ((size_t)bb*N_TOK + q0 + w*32 + q2)*C_ + h*64 + dh*32;
  #pragma unroll
  for (int i = 0; i < 4; i++){
    s16x8 ob;
    #pragma unroll
    for (int e = 0; e < 8; e++) ob[e] = (short)f2bf(of[i*8+e]);
    *(s16x8*)(orow + i*8) = ob;
  }
}

extern "C" void kernel_launch(void* const* d_in, const int* in_sizes, int n_in,
                              void* d_out, int out_size, void* d_ws, size_t ws_size,
                              hipStream_t stream) {
  const float* x      = (const float*)d_in[0];
  const int*   mask   = (const int*)  d_in[1];
  const float* relb   = (const float*)d_in[2];
  const float* w_qkv  = (const float*)d_in[3];
  const float* q_bias = (const float*)d_in[4];
  const float* v_bias = (const float*)d_in[5];
  const float* w_proj = (const float*)d_in[6];
  const float* b_proj = (const float*)d_in[7];
  const float* ln1_g  = (const float*)d_in[8];
  const float* ln1_b  = (const float*)d_in[9];
  const float* ln2t_g = (const float*)d_in[10];
  const float* ln2t_b = (const float*)d_in[11];
  const float* ln2i_g = (const float*)d_in[12];
  const float* ln2i_b = (const float*)d_in[13];
  const float* w1t    = (const float*)d_in[14];
  const float* b1t    = (const float*)d_in[15];
  const float* w2t    = (const float*)d_in[16];
  const float* b2t    = (const float*)d_in[17];
  const float* w1i    = (const float*)d_in[18];
  const float* b1i    = (const float*)d_in[19];
  const float* w2i    = (const float*)d_in[20];
  const float* b2i    = (const float*)d_in[21];
  const float* gamma1 = (const float*)d_in[22];
  const float* gamma2 = (const float*)d_in[23];
  float* out = (float*)d_out;
  char* ws = (char*)d_ws;

  size_t off = 0;
  auto nxt = [&](size_t b){ size_t r = off; off += (b + 255) & ~(size_t)255; return r; };
  unsigned short* wq_bf  = (unsigned short*)(ws + nxt((size_t)3*C_*C_*2));
  unsigned short* wp_bf  = (unsigned short*)(ws + nxt((size_t)C_*C_*2));
  unsigned short* w1t_bf = (unsigned short*)(ws + nxt((size_t)HID_*C_*2));
  unsigned short* w2t_bf = (unsigned short*)(ws + nxt((size_t)HID_*C_*2));
  unsigned short* w1i_bf = (unsigned short*)(ws + nxt((size_t)HID_*C_*2));
  unsigned short* w2i_bf = (unsigned short*)(ws + nxt((size_t)HID_*C_*2));
  unsigned short* hln    = (unsigned short*)(ws + nxt((size_t)B_*N_TOK*C_*2));   // reused as ln2c
  unsigned short* qkv    = (unsigned short*)(ws + nxt((size_t)3*B_*N_TOK*C_*2)); // reused as hidden
  unsigned short* attno  = (unsigned short*)(ws + nxt((size_t)B_*N_TOK*C_*2));
  float*          xmid   = (float*)(ws + nxt((size_t)B_*N_TOK*C_*4));
  unsigned short* ln2c   = hln;
  unsigned short* hidden = qkv;
  // bias_bf [H][N][N] bf16 overlays xmid exactly (both 25165824 B); attention reads it
  // BEFORE proj writes xmid — stream-ordered, deterministic across graph replays.
  unsigned short* bias_bf = (unsigned short*)xmid;

  // conversions + LN1 fused: 23808 convert blocks + 2048 LN1 blocks
  k_cvtall<<<dim3(25856), 256, 0, stream>>>(w_qkv, w_proj, w1t, w2t, w1i, w2i, relb,
                                            wq_bf, wp_bf, w1t_bf, w2t_bf, w1i_bf, w2i_bf, bias_bf,
                                            x, ln1_g, ln1_b, hln);

  // QKV GEMM: [8192][768] @ [2304][768]^T  (256-row tile, q*0.125 in epilogue)
  k_gemm2<0,256><<<dim3(32, 18, 1), 512, 0, stream>>>(hln, wq_bf, nullptr, C_,
                                                      q_bias, nullptr, v_bias,
                                                      nullptr, nullptr, qkv, nullptr);

  // attention (1D grid, XCD-aware decode in-kernel)
  const size_t qsz = (size_t)B_*H_*N_TOK*D_;
  k_attn<<<dim3(768), 256, 0, stream>>>(qkv, qkv + qsz, qkv + 2*qsz, bias_bf, mask, attno);

  // proj + residual -> xmid (fp32)
  k_gemm2<1,128><<<dim3(64, 6, 1), 256, 0, stream>>>(attno, wp_bf, nullptr, C_,
                                                     b_proj, nullptr, nullptr,
                                                     x, gamma1, nullptr, xmid);

  // LN2 (compacted text/image)
  k_ln2<<<dim3(B_*N_TOK/4), 256, 0, stream>>>(xmid, ln2t_g, ln2t_b, ln2i_g, ln2i_b, ln2c);

  // MLP fc1 + exact GELU (256-row tile; text z=0, image z=1)
  k_gemm2<2,256><<<dim3(16, 24, 2), 512, 0, stream>>>(ln2c, w1t_bf, w1i_bf, C_,
                                                      b1t, b1i, nullptr,
                                                      nullptr, nullptr, hidden, nullptr);

  // MLP fc2 + residual -> d_out (text z=0, image z=1)
  k_gemm2<3,128><<<dim3(32, 6, 2), 256, 0, stream>>>(hidden, w2t_bf, w2i_bf, HID_,
                                                     b2t, b2i, nullptr,
                                                     xmid, gamma2, nullptr, out);
}